// Round 8
// baseline (542.268 us; speedup 1.0000x reference)
//
#include <hip/hip_runtime.h>
#include <stdint.h>

// ScaledDotProductAttention: B=16, Nq=Nk=4096, d=128, fp32 in/out, causal.
// Flash forward, bf16 MFMA 16x16x32, swapped-QK^T (lane-local softmax).
// Round-7: occupancy push. Single-buffer 32KB LDS -> 4 blocks/CU (16 waves/CU,
// was 2 blocks/8 waves). Grid 1024: EVERY q-tile's kv range is split in half
// (chunk0 raw f32 -> O, chunk1 bf16 -> Pa, uniform 2-way merge). Bid mapping
// gives each CU 4 blocks summing to 66 kv-units and keeps batch->XCD pinning.
// ws: Kfrag 16MB | Vfrag 16MB | Pa 16MB | Ml 1MB (fallback to unsplit if less).

#define NB 16
#define NS 4096
#define DH 128
#define FRAG_U16 8192  // u16 elems per (batch, kv-block-of-64) fragment tile (16KB)

typedef float          fx4   __attribute__((ext_vector_type(4)));
typedef uint32_t       ux4   __attribute__((ext_vector_type(4)));
typedef __bf16         bfv8  __attribute__((ext_vector_type(8)));
typedef __bf16         bfv4  __attribute__((ext_vector_type(4)));
typedef unsigned short u16x4 __attribute__((ext_vector_type(4)));

typedef const uint32_t __attribute__((address_space(1))) glob_u32;
typedef uint32_t       __attribute__((address_space(3))) lds_u32;

__device__ __forceinline__ fx4 mfma16(bfv8 a, bfv8 b, fx4 c) {
  return __builtin_amdgcn_mfma_f32_16x16x32_bf16(a, b, c, 0, 0, 0);
}

// ---------------- fused prepass: K,V fp32 -> fragment-packed bf16 ----------------
// One block per (batch, kv-block-of-64). Fragment layouts (lane = g*16+ln16):
//  Kfrag[b][kvblk][tt(4)][c(4)][lane(64)][8]: K[b][kvb+16tt+ln16][32c+8g+e]
//  Vfrag[b][kvblk][dt(8)][c(2)][lane(64)][8]: V^T row d=16dt+ln16,
//      kv elems: e<4 -> kvb+32c+4g+e ; e>=4 -> kvb+32c+16+4g+(e-4)
__global__ void __launch_bounds__(256) prepack_kernel(
    const float* __restrict__ K, const float* __restrict__ V,
    unsigned short* __restrict__ Kf, unsigned short* __restrict__ Vf) {
  __shared__ __align__(16) unsigned short tile[64][136];  // V kv x d, +8 pad
  const int bid = blockIdx.x;
  const int b = bid >> 6, kvblk = bid & 63;
  const int kvb = kvblk << 6;
  const int tid = threadIdx.x;
  const size_t fbase = ((size_t)(b * 64 + kvblk)) * FRAG_U16;

  // ---- K fragments ----
  {
    const int tt = tid >> 6, lane = tid & 63;
    const int ln16 = lane & 15, g = lane >> 4;
    const float* kp = K + (((size_t)(b * NS + kvb + 16 * tt + ln16)) << 7) + 8 * g;
    unsigned short* op = Kf + fbase + tt * 2048 + lane * 8;
#pragma unroll
    for (int c = 0; c < 4; ++c) {
      fx4 a0 = *(const fx4*)(kp + 32 * c);
      fx4 a1 = *(const fx4*)(kp + 32 * c + 4);
      bfv8 t;
#pragma unroll
      for (int j = 0; j < 4; ++j) {
        t[j]     = (__bf16)a0[j];
        t[j + 4] = (__bf16)a1[j];
      }
      *(ux4*)(op + c * 512) = __builtin_bit_cast(ux4, t);
    }
  }

  // ---- V: stage bf16 tile in LDS, then gather-write fragments ----
  {
    const int r = tid >> 2, cq = tid & 3;
    const float* vp = V + (((size_t)(b * NS + kvb + r)) << 7) + 32 * cq;
#pragma unroll
    for (int h = 0; h < 4; ++h) {
      fx4 f0 = *(const fx4*)(vp + 8 * h);
      fx4 f1 = *(const fx4*)(vp + 8 * h + 4);
      bfv8 t;
#pragma unroll
      for (int j = 0; j < 4; ++j) {
        t[j]     = (__bf16)f0[j];
        t[j + 4] = (__bf16)f1[j];
      }
      *(ux4*)&tile[r][32 * cq + 8 * h] = __builtin_bit_cast(ux4, t);
    }
  }
  __syncthreads();
  {
    const int dt = tid >> 5, c = (tid >> 4) & 1, ln16 = tid & 15;
    const int d = 16 * dt + ln16;
    unsigned short* op = Vf + fbase + dt * 1024 + c * 512 + ln16 * 8;
#pragma unroll
    for (int g = 0; g < 4; ++g) {
      unsigned short e[8];
#pragma unroll
      for (int j = 0; j < 4; ++j) {
        e[j]     = tile[32 * c + 4 * g + j][d];
        e[j + 4] = tile[32 * c + 16 + 4 * g + j][d];
      }
      *(ux4*)(op + g * 128) = *(const ux4*)e;  // lane*8 = (g*16+ln16)*8
    }
  }
}

// ---------------- main: causal flash attention, 4 blocks/CU ----------------
// Worker decode (split): wid = G*256 + v*16 + b, G=0..3:
//   G0: chunk0 of t=31-v   G1: chunk0 of t=v
//   G2: chunk1 of t=31-v   G3: chunk1 of t=v
// Round-robin CU assignment {c, c+256, c+512, c+768} then sums to 66 units.
// chunk0 = kv blocks [0, t+1)  -> raw f32 acc to O, (m,l) to Ml slot0
// chunk1 = kv blocks [t+1,2t+2)-> bf16 acc to Pa,   (m,l) to Ml slot1
__global__ void __launch_bounds__(256, 4) attn_kernel(
    const float* __restrict__ Q, const unsigned short* __restrict__ Kf,
    const unsigned short* __restrict__ Vf, float* __restrict__ O,
    unsigned short* __restrict__ Pa, float* __restrict__ Ml, int split) {
  __shared__ __align__(16) unsigned char sm[32768];  // single buffer: K 16K | V 16K

  const int wid  = blockIdx.x;
  const int tid  = threadIdx.x;
  const int w    = tid >> 6;
  const int lane = tid & 63;
  const int g    = lane >> 4;
  const int ln16 = lane & 15;

  int b, t, j0, nc, mode;
  if (split) {
    const int G = wid >> 8;
    const int v = (wid >> 4) & 15;
    b = wid & 15;                       // wid%8 = b%8 -> XCD pin, 2 batches/XCD
    t = (G & 1) ? v : 31 - v;
    const int ih = G >> 1;
    j0 = ih ? (t + 1) : 0;
    nc = t + 1;
    mode = 1 + ih;
  } else {  // fallback: round-5 static pairing, no partials (grid 512)
    const int half = wid >> 8, ii = wid & 255;
    b = ii & 15;
    const int qi = ii >> 4;
    t = half ? qi : 31 - qi;
    j0 = 0; nc = 2 * t + 2; mode = 0;
  }

  const float SCALE = 0.12753102f;  // log2(e)/sqrt(128): exp2-domain scores
  const fx4 z4 = {0.f, 0.f, 0.f, 0.f};

  const unsigned short* kfb = Kf + ((size_t)b * 64) * FRAG_U16;
  const unsigned short* vfb = Vf + ((size_t)b * 64) * FRAG_U16;

  const int qb = t << 7;
  const int qw = qb + 32 * w;

  // Q fragments, pre-scaled, in registers for the whole kernel.
  bfv8 qf[2][4];
#pragma unroll
  for (int qt = 0; qt < 2; ++qt) {
#pragma unroll
    for (int c = 0; c < 4; ++c) {
      const float* qp = Q + (((size_t)(b * NS + qw + qt * 16 + ln16)) << 7) + 32 * c + 8 * g;
      fx4 a0 = *(const fx4*)qp;
      fx4 a1 = *(const fx4*)(qp + 4);
      bfv8 tt_;
#pragma unroll
      for (int j = 0; j < 4; ++j) {
        tt_[j]     = (__bf16)(a0[j] * SCALE);
        tt_[j + 4] = (__bf16)(a1[j] * SCALE);
      }
      qf[qt][c] = tt_;
    }
  }

  fx4 acc[2][8];
#pragma unroll
  for (int qt = 0; qt < 2; ++qt)
#pragma unroll
    for (int dt = 0; dt < 8; ++dt) acc[qt][dt] = z4;
  float mrun[2] = {-1e30f, -1e30f};
  float lsum[2] = {0.f, 0.f};

  const int nkvw = ((qw + 31) >> 6) + 1;  // causal limit (absolute kv blocks)
  const int jend = j0 + nc;

  // stage kv-block jb into the single LDS buffer. Wave w moves 1KB chunks:
  // lds dst is wave-uniform, HW adds lane*16.
#define STAGE(jb)                                                              \
  do {                                                                         \
    const unsigned char* gk = (const unsigned char*)(kfb + (size_t)(jb)*FRAG_U16); \
    const unsigned char* gv = (const unsigned char*)(vfb + (size_t)(jb)*FRAG_U16); \
    _Pragma("unroll")                                                          \
    for (int ii = 0; ii < 4; ++ii) {                                           \
      const int off = ii * 4096 + w * 1024;                                    \
      __builtin_amdgcn_global_load_lds((glob_u32*)(gk + off + lane * 16),      \
                                       (lds_u32*)(sm + off), 16, 0, 0);        \
      __builtin_amdgcn_global_load_lds((glob_u32*)(gv + off + lane * 16),      \
                                       (lds_u32*)(sm + 16384 + off), 16, 0, 0); \
    }                                                                          \
  } while (0)

  // prologue: stage first tile
  STAGE(j0);
  asm volatile("s_waitcnt vmcnt(0)" ::: "memory");
  __builtin_amdgcn_s_barrier();
  asm volatile("" ::: "memory");

  for (int jb = j0; jb < jend; ++jb) {
    if (jb < nkvw) {
      const unsigned char* kb = sm;
      const unsigned char* vb = sm + 16384;

      // ---- QK^T (swapped: A=K rows->kv, B=Q cols->q) ----
      fx4 s[2][4];
#pragma unroll
      for (int tt = 0; tt < 4; ++tt) { s[0][tt] = z4; s[1][tt] = z4; }
      __builtin_amdgcn_s_setprio(1);
#pragma unroll
      for (int tt = 0; tt < 4; ++tt) {
#pragma unroll
        for (int c = 0; c < 4; ++c) {
          bfv8 kfr = *(const bfv8*)(kb + tt * 4096 + c * 1024 + lane * 16);
          s[0][tt] = mfma16(kfr, qf[0][c], s[0][tt]);
          s[1][tt] = mfma16(kfr, qf[1][c], s[1][tt]);
        }
      }
      __builtin_amdgcn_s_setprio(0);

      // ---- V fragments from LDS (compiler schedules; hides under softmax) ----
      bfv8 vfr[8][2];
#pragma unroll
      for (int dt = 0; dt < 8; ++dt)
#pragma unroll
        for (int c = 0; c < 2; ++c)
          vfr[dt][c] = *(const bfv8*)(vb + dt * 2048 + c * 1024 + lane * 16);

      // ---- causal mask (near-diagonal blocks only) ----
      const int kvb = jb << 6;
      if (kvb + 63 > qw) {
#pragma unroll
        for (int qt = 0; qt < 2; ++qt) {
          const int qrow = qw + qt * 16 + ln16;
#pragma unroll
          for (int tt = 0; tt < 4; ++tt)
#pragma unroll
            for (int r = 0; r < 4; ++r) {
              int kvpos = kvb + 16 * tt + 4 * g + r;
              if (kvpos > qrow) s[qt][tt][r] = -1e30f;
            }
        }
      }

      // ---- online softmax (exp2 domain, lane-local state, defer-max THR=8) ----
      bfv8 pb[2][2];
#pragma unroll
      for (int qt = 0; qt < 2; ++qt) {
        fx4 m4 = __builtin_elementwise_max(
            __builtin_elementwise_max(s[qt][0], s[qt][1]),
            __builtin_elementwise_max(s[qt][2], s[qt][3]));
        float pm = fmaxf(fmaxf(m4[0], m4[1]), fmaxf(m4[2], m4[3]));
        pm = fmaxf(pm, __shfl_xor(pm, 16));
        pm = fmaxf(pm, __shfl_xor(pm, 32));
        float mq = mrun[qt];
        if (__any(pm > mq + 8.0f)) {
          float mn = fmaxf(mq, pm);
          float f  = __builtin_amdgcn_exp2f(mq - mn);
          lsum[qt] *= f;
#pragma unroll
          for (int dt = 0; dt < 8; ++dt) acc[qt][dt] *= f;
          mrun[qt] = mn;
          mq = mn;
        }
#pragma unroll
        for (int tt = 0; tt < 4; ++tt)
#pragma unroll
          for (int r = 0; r < 4; ++r)
            s[qt][tt][r] = __builtin_amdgcn_exp2f(s[qt][tt][r] - mq);
        fx4 r4 = (s[qt][0] + s[qt][1]) + (s[qt][2] + s[qt][3]);
        float rs = (r4[0] + r4[1]) + (r4[2] + r4[3]);
        rs += __shfl_xor(rs, 16);
        rs += __shfl_xor(rs, 32);
        lsum[qt] += rs;
        // pack P^T: chunk c elem j<4 -> kv 32c+4g+j (tile 2c), j>=4 ->
        // 32c+16+4g+(j-4) (tile 2c+1) — matches Vfrag elem map exactly.
#pragma unroll
        for (int c = 0; c < 2; ++c) {
          bfv8 tt_;
#pragma unroll
          for (int j = 0; j < 4; ++j) {
            tt_[j]     = (__bf16)s[qt][2 * c][j];
            tt_[j + 4] = (__bf16)s[qt][2 * c + 1][j];
          }
          pb[qt][c] = tt_;
        }
      }

      // ---- PV (A = V^T rows->d, B = P^T cols->q) ----
      __builtin_amdgcn_s_setprio(1);
#pragma unroll
      for (int dt = 0; dt < 8; ++dt) {
#pragma unroll
        for (int c = 0; c < 2; ++c) {
          acc[0][dt] = mfma16(vfr[dt][c], pb[0][c], acc[0][dt]);
          acc[1][dt] = mfma16(vfr[dt][c], pb[1][c], acc[1][dt]);
        }
      }
      __builtin_amdgcn_s_setprio(0);
    }

    // barrier B: all waves done reading this tile; then overwrite it.
    asm volatile("" ::: "memory");
    __builtin_amdgcn_s_barrier();
    if (jb + 1 < jend) {
      STAGE(jb + 1);
      asm volatile("s_waitcnt vmcnt(0)" ::: "memory");
    }
    // barrier A: next tile fully staged for all waves.
    __builtin_amdgcn_s_barrier();
    asm volatile("" ::: "memory");
  }
#undef STAGE

  // ---- epilogue per mode ----
  if (mode == 0) {  // final: O = acc/l
#pragma unroll
    for (int qt = 0; qt < 2; ++qt) {
      float inv = 1.0f / lsum[qt];
      float* ob = O + (((size_t)(b * NS + qw + qt * 16 + ln16)) << 7) + 4 * g;
#pragma unroll
      for (int dt = 0; dt < 8; ++dt) *(fx4*)(ob + 16 * dt) = acc[qt][dt] * inv;
    }
  } else {
    if (mode == 1) {  // chunk0: raw f32 acc -> O (merged later)
#pragma unroll
      for (int qt = 0; qt < 2; ++qt) {
        float* ob = O + (((size_t)(b * NS + qw + qt * 16 + ln16)) << 7) + 4 * g;
#pragma unroll
        for (int dt = 0; dt < 8; ++dt) *(fx4*)(ob + 16 * dt) = acc[qt][dt];
      }
    } else {  // chunk1: bf16 acc -> Pa
#pragma unroll
      for (int qt = 0; qt < 2; ++qt) {
        const int row = 32 * w + 16 * qt + ln16;
        unsigned short* pp =
            Pa + (((size_t)((b * 32 + t) * 128 + row)) << 7) + 4 * g;
#pragma unroll
        for (int dt = 0; dt < 8; ++dt) {
          bfv4 t4;
#pragma unroll
          for (int j = 0; j < 4; ++j) t4[j] = (__bf16)acc[qt][dt][j];
          *(u16x4*)(pp + 16 * dt) = __builtin_bit_cast(u16x4, t4);
        }
      }
    }
    if (g == 0) {  // (m,l): Ml[b][t][slot][2][128]
      const int slot = mode - 1;
      float* mlp = Ml + (size_t)(((b * 32 + t) * 2 + slot) * 2) * 128;
#pragma unroll
      for (int qt = 0; qt < 2; ++qt) {
        const int row = 32 * w + 16 * qt + ln16;
        mlp[row]       = mrun[qt];
        mlp[128 + row] = lsum[qt];
      }
    }
  }
}

// ---------------- merge: combine chunk0 (raw f32 in O) with chunk1 (bf16 Pa) ----------------
__global__ void __launch_bounds__(256) merge_kernel(
    float* __restrict__ O, const unsigned short* __restrict__ Pa,
    const float* __restrict__ Ml) {
  const int gid = blockIdx.x * 256 + threadIdx.x;  // 2,097,152 threads exact
  const int d4  = gid & 31;
  const int rg  = gid >> 5;       // global row id, 0..65535
  const int b   = rg >> 12;
  const int r2  = rg & 4095;
  const int t   = r2 >> 7;
  const int row = r2 & 127;

  const float* mlp = Ml + (size_t)((b * 32 + t) * 4) * 128;
  const float m1 = mlp[row],       l1 = mlp[128 + row];
  const float m2 = mlp[256 + row], l2 = mlp[384 + row];
  const float m  = fmaxf(m1, m2);
  const float w1 = __builtin_amdgcn_exp2f(m1 - m);
  const float w2 = __builtin_amdgcn_exp2f(m2 - m);

  float* op = O + (((size_t)(b * NS + (t << 7) + row)) << 7) + 4 * d4;
  fx4 a1 = *(const fx4*)op;
  const unsigned short* pp =
      Pa + (((size_t)((b * 32 + t) * 128 + row)) << 7) + 4 * d4;
  bfv4 a2b = __builtin_bit_cast(bfv4, *(const u16x4*)pp);
  fx4 a2;
#pragma unroll
  for (int j = 0; j < 4; ++j) a2[j] = (float)a2b[j];

  const float inv = 1.0f / (w1 * l1 + w2 * l2);
  fx4 o = (a1 * w1 + a2 * w2) * inv;
  *(fx4*)op = o;
}

extern "C" void kernel_launch(void* const* d_in, const int* in_sizes, int n_in,
                              void* d_out, int out_size, void* d_ws, size_t ws_size,
                              hipStream_t stream) {
  (void)in_sizes; (void)n_in; (void)out_size;
  const float* Q = (const float*)d_in[0];
  const float* K = (const float*)d_in[1];
  const float* V = (const float*)d_in[2];
  float* O = (float*)d_out;

  unsigned short* Kf = (unsigned short*)d_ws;               // 16 MB
  unsigned short* Vf = Kf + (size_t)NB * NS * DH;           // +16 MB
  unsigned short* Pa = Vf + (size_t)NB * NS * DH;           // +16 MB (bf16 partials)
  float*          Ml = (float*)((char*)d_ws + 50331648);    // +1 MB (m,l)

  const size_t NEED = 50331648 + 1048576;  // 51,380,224 B
  const int split = (ws_size >= NEED) ? 1 : 0;

  prepack_kernel<<<dim3(NB * 64), dim3(256), 0, stream>>>(K, V, Kf, Vf);
  attn_kernel<<<dim3(split ? 1024 : 512), dim3(256), 0, stream>>>(
      Q, Kf, Vf, O, Pa, Ml, split);
  if (split) merge_kernel<<<dim3(8192), dim3(256), 0, stream>>>(O, Pa, Ml);
}

// Round 9
// 348.745 us; speedup vs baseline: 1.5549x; 1.5549x over previous
//
#include <hip/hip_runtime.h>
#include <stdint.h>

// ScaledDotProductAttention: B=16, Nq=Nk=4096, d=128, fp32 in/out, causal.
// Flash forward, bf16 MFMA 16x16x32, swapped-QK^T (lane-local softmax).
// Round-8: 3 blocks/CU. Single-buffer 32KB LDS + __launch_bounds__(256,3)
// (VGPR cap ~170 >= ~152 demand -> NO spill; round-7's (256,4) spilled and
// cost 2GB of scratch traffic). Grid 768 = 3 slots x 256: per (b,v):
//   slot0: full tile v          (2v+2 kv-units, mode 0, direct O)
//   slot1: tile 31-v kv[0,t+1)  (32-v units, mode 1, raw f32 -> O)
//   slot2: tile 31-v kv[t+1,2t+2) (32-v units, mode 2, bf16 -> Pa)
// Every CU slot-triple sums to 66 units. Merge = round-6 verified kernel.
// ws: Kfrag 16MB | Vfrag 16MB | Pa 8MB | Ml 0.5MB (fallback if smaller).

#define NB 16
#define NS 4096
#define DH 128
#define FRAG_U16 8192  // u16 elems per (batch, kv-block-of-64) fragment tile (16KB)

typedef float          fx4   __attribute__((ext_vector_type(4)));
typedef uint32_t       ux4   __attribute__((ext_vector_type(4)));
typedef __bf16         bfv8  __attribute__((ext_vector_type(8)));
typedef __bf16         bfv4  __attribute__((ext_vector_type(4)));
typedef unsigned short u16x4 __attribute__((ext_vector_type(4)));

typedef const uint32_t __attribute__((address_space(1))) glob_u32;
typedef uint32_t       __attribute__((address_space(3))) lds_u32;

__device__ __forceinline__ fx4 mfma16(bfv8 a, bfv8 b, fx4 c) {
  return __builtin_amdgcn_mfma_f32_16x16x32_bf16(a, b, c, 0, 0, 0);
}

// ---------------- fused prepass: K,V fp32 -> fragment-packed bf16 ----------------
// One block per (batch, kv-block-of-64). Fragment layouts (lane = g*16+ln16):
//  Kfrag[b][kvblk][tt(4)][c(4)][lane(64)][8]: K[b][kvb+16tt+ln16][32c+8g+e]
//  Vfrag[b][kvblk][dt(8)][c(2)][lane(64)][8]: V^T row d=16dt+ln16,
//      kv elems: e<4 -> kvb+32c+4g+e ; e>=4 -> kvb+32c+16+4g+(e-4)
__global__ void __launch_bounds__(256) prepack_kernel(
    const float* __restrict__ K, const float* __restrict__ V,
    unsigned short* __restrict__ Kf, unsigned short* __restrict__ Vf) {
  __shared__ __align__(16) unsigned short tile[64][136];  // V kv x d, +8 pad
  const int bid = blockIdx.x;
  const int b = bid >> 6, kvblk = bid & 63;
  const int kvb = kvblk << 6;
  const int tid = threadIdx.x;
  const size_t fbase = ((size_t)(b * 64 + kvblk)) * FRAG_U16;

  // ---- K fragments ----
  {
    const int tt = tid >> 6, lane = tid & 63;
    const int ln16 = lane & 15, g = lane >> 4;
    const float* kp = K + (((size_t)(b * NS + kvb + 16 * tt + ln16)) << 7) + 8 * g;
    unsigned short* op = Kf + fbase + tt * 2048 + lane * 8;
#pragma unroll
    for (int c = 0; c < 4; ++c) {
      fx4 a0 = *(const fx4*)(kp + 32 * c);
      fx4 a1 = *(const fx4*)(kp + 32 * c + 4);
      bfv8 t;
#pragma unroll
      for (int j = 0; j < 4; ++j) {
        t[j]     = (__bf16)a0[j];
        t[j + 4] = (__bf16)a1[j];
      }
      *(ux4*)(op + c * 512) = __builtin_bit_cast(ux4, t);
    }
  }

  // ---- V: stage bf16 tile in LDS, then gather-write fragments ----
  {
    const int r = tid >> 2, cq = tid & 3;
    const float* vp = V + (((size_t)(b * NS + kvb + r)) << 7) + 32 * cq;
#pragma unroll
    for (int h = 0; h < 4; ++h) {
      fx4 f0 = *(const fx4*)(vp + 8 * h);
      fx4 f1 = *(const fx4*)(vp + 8 * h + 4);
      bfv8 t;
#pragma unroll
      for (int j = 0; j < 4; ++j) {
        t[j]     = (__bf16)f0[j];
        t[j + 4] = (__bf16)f1[j];
      }
      *(ux4*)&tile[r][32 * cq + 8 * h] = __builtin_bit_cast(ux4, t);
    }
  }
  __syncthreads();
  {
    const int dt = tid >> 5, c = (tid >> 4) & 1, ln16 = tid & 15;
    const int d = 16 * dt + ln16;
    unsigned short* op = Vf + fbase + dt * 1024 + c * 512 + ln16 * 8;
#pragma unroll
    for (int g = 0; g < 4; ++g) {
      unsigned short e[8];
#pragma unroll
      for (int j = 0; j < 4; ++j) {
        e[j]     = tile[32 * c + 4 * g + j][d];
        e[j + 4] = tile[32 * c + 16 + 4 * g + j][d];
      }
      *(ux4*)(op + g * 128) = *(const ux4*)e;  // lane*8 = (g*16+ln16)*8
    }
  }
}

// ---------------- main: causal flash attention, 3 blocks/CU ----------------
__global__ void __launch_bounds__(256, 3) attn_kernel(
    const float* __restrict__ Q, const unsigned short* __restrict__ Kf,
    const unsigned short* __restrict__ Vf, float* __restrict__ O,
    unsigned short* __restrict__ Pa, float* __restrict__ Ml, int split) {
  __shared__ __align__(16) unsigned char sm[32768];  // single buffer: K 16K | V 16K

  const int wid  = blockIdx.x;
  const int tid  = threadIdx.x;
  const int w    = tid >> 6;
  const int lane = tid & 63;
  const int g    = lane >> 4;
  const int ln16 = lane & 15;

  int b, t, j0, nc, mode;
  if (split) {
    const int slot = wid >> 8;          // 0,1,2
    const int v    = (wid >> 4) & 15;
    b = wid & 15;                       // wid%8 = b%8 -> XCD pin, 2 batches/XCD
    if (slot == 0) {
      t = v; j0 = 0; nc = 2 * v + 2; mode = 0;          // full small tile
    } else {
      t = 31 - v;                                        // big tile, 2 chunks
      j0 = (slot == 1) ? 0 : (t + 1);
      nc = t + 1;
      mode = slot;                                       // 1: raw->O, 2: bf16->Pa
    }
  } else {  // fallback: round-5 static pairing, no partials (grid 512)
    const int half = wid >> 8, ii = wid & 255;
    b = ii & 15;
    const int qi = ii >> 4;
    t = half ? qi : 31 - qi;
    j0 = 0; nc = 2 * t + 2; mode = 0;
  }

  const float SCALE = 0.12753102f;  // log2(e)/sqrt(128): exp2-domain scores
  const fx4 z4 = {0.f, 0.f, 0.f, 0.f};

  const unsigned short* kfb = Kf + ((size_t)b * 64) * FRAG_U16;
  const unsigned short* vfb = Vf + ((size_t)b * 64) * FRAG_U16;

  const int qb = t << 7;
  const int qw = qb + 32 * w;

  // Q fragments, pre-scaled, in registers for the whole kernel.
  bfv8 qf[2][4];
#pragma unroll
  for (int qt = 0; qt < 2; ++qt) {
#pragma unroll
    for (int c = 0; c < 4; ++c) {
      const float* qp = Q + (((size_t)(b * NS + qw + qt * 16 + ln16)) << 7) + 32 * c + 8 * g;
      fx4 a0 = *(const fx4*)qp;
      fx4 a1 = *(const fx4*)(qp + 4);
      bfv8 tt_;
#pragma unroll
      for (int j = 0; j < 4; ++j) {
        tt_[j]     = (__bf16)(a0[j] * SCALE);
        tt_[j + 4] = (__bf16)(a1[j] * SCALE);
      }
      qf[qt][c] = tt_;
    }
  }

  fx4 acc[2][8];
#pragma unroll
  for (int qt = 0; qt < 2; ++qt)
#pragma unroll
    for (int dt = 0; dt < 8; ++dt) acc[qt][dt] = z4;
  float mrun[2] = {-1e30f, -1e30f};
  float lsum[2] = {0.f, 0.f};

  const int nkvw = ((qw + 31) >> 6) + 1;  // causal limit (absolute kv blocks)
  const int jend = j0 + nc;

  // stage kv-block jb into the single LDS buffer. Wave w moves 1KB chunks:
  // lds dst is wave-uniform, HW adds lane*16.
#define STAGE(jb)                                                              \
  do {                                                                         \
    const unsigned char* gk = (const unsigned char*)(kfb + (size_t)(jb)*FRAG_U16); \
    const unsigned char* gv = (const unsigned char*)(vfb + (size_t)(jb)*FRAG_U16); \
    _Pragma("unroll")                                                          \
    for (int ii = 0; ii < 4; ++ii) {                                           \
      const int off = ii * 4096 + w * 1024;                                    \
      __builtin_amdgcn_global_load_lds((glob_u32*)(gk + off + lane * 16),      \
                                       (lds_u32*)(sm + off), 16, 0, 0);        \
      __builtin_amdgcn_global_load_lds((glob_u32*)(gv + off + lane * 16),      \
                                       (lds_u32*)(sm + 16384 + off), 16, 0, 0); \
    }                                                                          \
  } while (0)

  // prologue: stage first tile
  STAGE(j0);
  asm volatile("s_waitcnt vmcnt(0)" ::: "memory");
  __builtin_amdgcn_s_barrier();
  asm volatile("" ::: "memory");

  for (int jb = j0; jb < jend; ++jb) {
    if (jb < nkvw) {
      const unsigned char* kb = sm;
      const unsigned char* vb = sm + 16384;

      // ---- QK^T (swapped: A=K rows->kv, B=Q cols->q) ----
      fx4 s[2][4];
#pragma unroll
      for (int tt = 0; tt < 4; ++tt) { s[0][tt] = z4; s[1][tt] = z4; }
      __builtin_amdgcn_s_setprio(1);
#pragma unroll
      for (int tt = 0; tt < 4; ++tt) {
#pragma unroll
        for (int c = 0; c < 4; ++c) {
          bfv8 kfr = *(const bfv8*)(kb + tt * 4096 + c * 1024 + lane * 16);
          s[0][tt] = mfma16(kfr, qf[0][c], s[0][tt]);
          s[1][tt] = mfma16(kfr, qf[1][c], s[1][tt]);
        }
      }
      __builtin_amdgcn_s_setprio(0);

      // ---- V fragments from LDS (compiler schedules; hides under softmax) ----
      bfv8 vfr[8][2];
#pragma unroll
      for (int dt = 0; dt < 8; ++dt)
#pragma unroll
        for (int c = 0; c < 2; ++c)
          vfr[dt][c] = *(const bfv8*)(vb + dt * 2048 + c * 1024 + lane * 16);

      // ---- causal mask (near-diagonal blocks only) ----
      const int kvb = jb << 6;
      if (kvb + 63 > qw) {
#pragma unroll
        for (int qt = 0; qt < 2; ++qt) {
          const int qrow = qw + qt * 16 + ln16;
#pragma unroll
          for (int tt = 0; tt < 4; ++tt)
#pragma unroll
            for (int r = 0; r < 4; ++r) {
              int kvpos = kvb + 16 * tt + 4 * g + r;
              if (kvpos > qrow) s[qt][tt][r] = -1e30f;
            }
        }
      }

      // ---- online softmax (exp2 domain, lane-local state, defer-max THR=8) ----
      bfv8 pb[2][2];
#pragma unroll
      for (int qt = 0; qt < 2; ++qt) {
        fx4 m4 = __builtin_elementwise_max(
            __builtin_elementwise_max(s[qt][0], s[qt][1]),
            __builtin_elementwise_max(s[qt][2], s[qt][3]));
        float pm = fmaxf(fmaxf(m4[0], m4[1]), fmaxf(m4[2], m4[3]));
        pm = fmaxf(pm, __shfl_xor(pm, 16));
        pm = fmaxf(pm, __shfl_xor(pm, 32));
        float mq = mrun[qt];
        if (__any(pm > mq + 8.0f)) {
          float mn = fmaxf(mq, pm);
          float f  = __builtin_amdgcn_exp2f(mq - mn);
          lsum[qt] *= f;
#pragma unroll
          for (int dt = 0; dt < 8; ++dt) acc[qt][dt] *= f;
          mrun[qt] = mn;
          mq = mn;
        }
#pragma unroll
        for (int tt = 0; tt < 4; ++tt)
#pragma unroll
          for (int r = 0; r < 4; ++r)
            s[qt][tt][r] = __builtin_amdgcn_exp2f(s[qt][tt][r] - mq);
        fx4 r4 = (s[qt][0] + s[qt][1]) + (s[qt][2] + s[qt][3]);
        float rs = (r4[0] + r4[1]) + (r4[2] + r4[3]);
        rs += __shfl_xor(rs, 16);
        rs += __shfl_xor(rs, 32);
        lsum[qt] += rs;
        // pack P^T: chunk c elem j<4 -> kv 32c+4g+j (tile 2c), j>=4 ->
        // 32c+16+4g+(j-4) (tile 2c+1) — matches Vfrag elem map exactly.
#pragma unroll
        for (int c = 0; c < 2; ++c) {
          bfv8 tt_;
#pragma unroll
          for (int j = 0; j < 4; ++j) {
            tt_[j]     = (__bf16)s[qt][2 * c][j];
            tt_[j + 4] = (__bf16)s[qt][2 * c + 1][j];
          }
          pb[qt][c] = tt_;
        }
      }

      // ---- PV (A = V^T rows->d, B = P^T cols->q) ----
      __builtin_amdgcn_s_setprio(1);
#pragma unroll
      for (int dt = 0; dt < 8; ++dt) {
#pragma unroll
        for (int c = 0; c < 2; ++c) {
          acc[0][dt] = mfma16(vfr[dt][c], pb[0][c], acc[0][dt]);
          acc[1][dt] = mfma16(vfr[dt][c], pb[1][c], acc[1][dt]);
        }
      }
      __builtin_amdgcn_s_setprio(0);
    }

    // barrier B: all waves done reading this tile; then overwrite it.
    asm volatile("" ::: "memory");
    __builtin_amdgcn_s_barrier();
    if (jb + 1 < jend) {
      STAGE(jb + 1);
      asm volatile("s_waitcnt vmcnt(0)" ::: "memory");
    }
    // barrier A: next tile fully staged for all waves.
    __builtin_amdgcn_s_barrier();
    asm volatile("" ::: "memory");
  }
#undef STAGE

  // ---- epilogue per mode ----
  if (mode == 0) {  // final: O = acc/l
#pragma unroll
    for (int qt = 0; qt < 2; ++qt) {
      float inv = 1.0f / lsum[qt];
      float* ob = O + (((size_t)(b * NS + qw + qt * 16 + ln16)) << 7) + 4 * g;
#pragma unroll
      for (int dt = 0; dt < 8; ++dt) *(fx4*)(ob + 16 * dt) = acc[qt][dt] * inv;
    }
  } else {
    if (mode == 1) {  // chunk0: raw f32 acc -> O (merged later)
#pragma unroll
      for (int qt = 0; qt < 2; ++qt) {
        float* ob = O + (((size_t)(b * NS + qw + qt * 16 + ln16)) << 7) + 4 * g;
#pragma unroll
        for (int dt = 0; dt < 8; ++dt) *(fx4*)(ob + 16 * dt) = acc[qt][dt];
      }
    } else {  // chunk1: bf16 acc -> Pa
#pragma unroll
      for (int qt = 0; qt < 2; ++qt) {
        const int row = 32 * w + 16 * qt + ln16;
        unsigned short* pp =
            Pa + (((size_t)((b * 16 + (t - 16)) * 128 + row)) << 7) + 4 * g;
#pragma unroll
        for (int dt = 0; dt < 8; ++dt) {
          bfv4 t4;
#pragma unroll
          for (int j = 0; j < 4; ++j) t4[j] = (__bf16)acc[qt][dt][j];
          *(u16x4*)(pp + 16 * dt) = __builtin_bit_cast(u16x4, t4);
        }
      }
    }
    if (g == 0) {  // (m,l): Ml[b][t-16][slot][2][128]
      const int slot = mode - 1;
      float* mlp = Ml + (size_t)(((b * 16 + (t - 16)) * 2 + slot) * 2) * 128;
#pragma unroll
      for (int qt = 0; qt < 2; ++qt) {
        const int row = 32 * w + 16 * qt + ln16;
        mlp[row]       = mrun[qt];
        mlp[128 + row] = lsum[qt];
      }
    }
  }
}

// ---------------- merge: combine chunk0 (raw f32 in O) with chunk1 (bf16 Pa) ----------------
__global__ void __launch_bounds__(256) merge_kernel(
    float* __restrict__ O, const unsigned short* __restrict__ Pa,
    const float* __restrict__ Ml) {
  const int gid = blockIdx.x * 256 + threadIdx.x;  // 1,048,576 threads exact
  const int d4  = gid & 31;
  const int rg  = gid >> 5;       // global split-row id, 0..32767
  const int b   = rg >> 11;
  const int r2  = rg & 2047;
  const int tt  = r2 >> 7;        // tile t = 16+tt
  const int row = r2 & 127;

  const float* mlp = Ml + (size_t)((b * 16 + tt) * 4) * 128;
  const float m1 = mlp[row],       l1 = mlp[128 + row];
  const float m2 = mlp[256 + row], l2 = mlp[384 + row];
  const float m  = fmaxf(m1, m2);
  const float w1 = __builtin_amdgcn_exp2f(m1 - m);
  const float w2 = __builtin_amdgcn_exp2f(m2 - m);

  float* op = O + (((size_t)(b * NS + (16 + tt) * 128 + row)) << 7) + 4 * d4;
  fx4 a1 = *(const fx4*)op;
  const unsigned short* pp =
      Pa + (((size_t)((b * 16 + tt) * 128 + row)) << 7) + 4 * d4;
  bfv4 a2b = __builtin_bit_cast(bfv4, *(const u16x4*)pp);
  fx4 a2;
#pragma unroll
  for (int j = 0; j < 4; ++j) a2[j] = (float)a2b[j];

  const float inv = 1.0f / (w1 * l1 + w2 * l2);
  fx4 o = (a1 * w1 + a2 * w2) * inv;
  *(fx4*)op = o;
}

extern "C" void kernel_launch(void* const* d_in, const int* in_sizes, int n_in,
                              void* d_out, int out_size, void* d_ws, size_t ws_size,
                              hipStream_t stream) {
  (void)in_sizes; (void)n_in; (void)out_size;
  const float* Q = (const float*)d_in[0];
  const float* K = (const float*)d_in[1];
  const float* V = (const float*)d_in[2];
  float* O = (float*)d_out;

  unsigned short* Kf = (unsigned short*)d_ws;               // 16 MB
  unsigned short* Vf = Kf + (size_t)NB * NS * DH;           // +16 MB
  unsigned short* Pa = Vf + (size_t)NB * NS * DH;           // +8 MB  (bf16 partials)
  float*          Ml = (float*)((char*)d_ws + 41943040);    // +512 KB (m,l)

  const size_t NEED = 41943040 + 524288;  // 42,467,328 B
  const int split = (ws_size >= NEED) ? 1 : 0;

  prepack_kernel<<<dim3(NB * 64), dim3(256), 0, stream>>>(K, V, Kf, Vf);
  attn_kernel<<<dim3(split ? 768 : 512), dim3(256), 0, stream>>>(
      Q, Kf, Vf, O, Pa, Ml, split);
  if (split) merge_kernel<<<dim3(4096), dim3(256), 0, stream>>>(O, Pa, Ml);
}

// Round 10
// 124.262 us; speedup vs baseline: 4.3639x; 2.8065x over previous
//
#include <hip/hip_runtime.h>
#include <stdint.h>

// ScaledDotProductAttention: B=16, Nq=Nk=4096, d=128, fp32 in/out, causal.
// Flash forward, bf16 MFMA 16x16x32, swapped-QK^T (lane-local softmax).
// Round-9: fit 3 blocks/CU WITHOUT spilling. (256,3) total-reg cap ~168/wave
// = 64 acc (AGPR) + ~104 VGPR. Round-8 spilled because vfr[8][2] prefetch
// (+32 VGPR) pushed the live set to ~115 -> 650MB scratch traffic. This round
// reads V fragments inline in the PV loop (compiler pipelines ds_read_b128
// with counted lgkmcnt; 12 waves/CU hide the latency). Peak live ~95 VGPR.
// Work mapping (grid 768 = 3 slots x 256, all co-resident, 66 kv-units/CU):
//   slot0: full tile v           (2v+2 units, mode 0, direct O)
//   slot1: tile 31-v kv[0,t+1)   (32-v units, mode 1, raw f32 -> O)
//   slot2: tile 31-v kv[t+1,2t+2)(32-v units, mode 2, bf16 -> Pa)
// ws: Kfrag 16MB | Vfrag 16MB | Pa 8MB | Ml 0.5MB (fallback if smaller).

#define NB 16
#define NS 4096
#define DH 128
#define FRAG_U16 8192  // u16 elems per (batch, kv-block-of-64) fragment tile (16KB)

typedef float          fx4   __attribute__((ext_vector_type(4)));
typedef uint32_t       ux4   __attribute__((ext_vector_type(4)));
typedef __bf16         bfv8  __attribute__((ext_vector_type(8)));
typedef __bf16         bfv4  __attribute__((ext_vector_type(4)));
typedef unsigned short u16x4 __attribute__((ext_vector_type(4)));

typedef const uint32_t __attribute__((address_space(1))) glob_u32;
typedef uint32_t       __attribute__((address_space(3))) lds_u32;

__device__ __forceinline__ fx4 mfma16(bfv8 a, bfv8 b, fx4 c) {
  return __builtin_amdgcn_mfma_f32_16x16x32_bf16(a, b, c, 0, 0, 0);
}

// ---------------- fused prepass: K,V fp32 -> fragment-packed bf16 ----------------
// One block per (batch, kv-block-of-64). Fragment layouts (lane = g*16+ln16):
//  Kfrag[b][kvblk][tt(4)][c(4)][lane(64)][8]: K[b][kvb+16tt+ln16][32c+8g+e]
//  Vfrag[b][kvblk][dt(8)][c(2)][lane(64)][8]: V^T row d=16dt+ln16,
//      kv elems: e<4 -> kvb+32c+4g+e ; e>=4 -> kvb+32c+16+4g+(e-4)
__global__ void __launch_bounds__(256) prepack_kernel(
    const float* __restrict__ K, const float* __restrict__ V,
    unsigned short* __restrict__ Kf, unsigned short* __restrict__ Vf) {
  __shared__ __align__(16) unsigned short tile[64][136];  // V kv x d, +8 pad
  const int bid = blockIdx.x;
  const int b = bid >> 6, kvblk = bid & 63;
  const int kvb = kvblk << 6;
  const int tid = threadIdx.x;
  const size_t fbase = ((size_t)(b * 64 + kvblk)) * FRAG_U16;

  // ---- K fragments ----
  {
    const int tt = tid >> 6, lane = tid & 63;
    const int ln16 = lane & 15, g = lane >> 4;
    const float* kp = K + (((size_t)(b * NS + kvb + 16 * tt + ln16)) << 7) + 8 * g;
    unsigned short* op = Kf + fbase + tt * 2048 + lane * 8;
#pragma unroll
    for (int c = 0; c < 4; ++c) {
      fx4 a0 = *(const fx4*)(kp + 32 * c);
      fx4 a1 = *(const fx4*)(kp + 32 * c + 4);
      bfv8 t;
#pragma unroll
      for (int j = 0; j < 4; ++j) {
        t[j]     = (__bf16)a0[j];
        t[j + 4] = (__bf16)a1[j];
      }
      *(ux4*)(op + c * 512) = __builtin_bit_cast(ux4, t);
    }
  }

  // ---- V: stage bf16 tile in LDS, then gather-write fragments ----
  {
    const int r = tid >> 2, cq = tid & 3;
    const float* vp = V + (((size_t)(b * NS + kvb + r)) << 7) + 32 * cq;
#pragma unroll
    for (int h = 0; h < 4; ++h) {
      fx4 f0 = *(const fx4*)(vp + 8 * h);
      fx4 f1 = *(const fx4*)(vp + 8 * h + 4);
      bfv8 t;
#pragma unroll
      for (int j = 0; j < 4; ++j) {
        t[j]     = (__bf16)f0[j];
        t[j + 4] = (__bf16)f1[j];
      }
      *(ux4*)&tile[r][32 * cq + 8 * h] = __builtin_bit_cast(ux4, t);
    }
  }
  __syncthreads();
  {
    const int dt = tid >> 5, c = (tid >> 4) & 1, ln16 = tid & 15;
    const int d = 16 * dt + ln16;
    unsigned short* op = Vf + fbase + dt * 1024 + c * 512 + ln16 * 8;
#pragma unroll
    for (int g = 0; g < 4; ++g) {
      unsigned short e[8];
#pragma unroll
      for (int j = 0; j < 4; ++j) {
        e[j]     = tile[32 * c + 4 * g + j][d];
        e[j + 4] = tile[32 * c + 16 + 4 * g + j][d];
      }
      *(ux4*)(op + g * 128) = *(const ux4*)e;  // lane*8 = (g*16+ln16)*8
    }
  }
}

// ---------------- main: causal flash attention, 3 blocks/CU, no spill ----------------
__global__ void __launch_bounds__(256, 3) attn_kernel(
    const float* __restrict__ Q, const unsigned short* __restrict__ Kf,
    const unsigned short* __restrict__ Vf, float* __restrict__ O,
    unsigned short* __restrict__ Pa, float* __restrict__ Ml, int split) {
  __shared__ __align__(16) unsigned char sm[32768];  // single buffer: K 16K | V 16K

  const int wid  = blockIdx.x;
  const int tid  = threadIdx.x;
  const int w    = tid >> 6;
  const int lane = tid & 63;
  const int g    = lane >> 4;
  const int ln16 = lane & 15;

  int b, t, j0, nc, mode;
  if (split) {
    const int slot = wid >> 8;          // 0,1,2
    const int v    = (wid >> 4) & 15;
    b = wid & 15;                       // wid%8 = b%8 -> XCD pin, 2 batches/XCD
    if (slot == 0) {
      t = v; j0 = 0; nc = 2 * v + 2; mode = 0;          // full small tile
    } else {
      t = 31 - v;                                        // big tile, 2 chunks
      j0 = (slot == 1) ? 0 : (t + 1);
      nc = t + 1;
      mode = slot;                                       // 1: raw->O, 2: bf16->Pa
    }
  } else {  // fallback: round-5 static pairing, no partials (grid 512)
    const int half = wid >> 8, ii = wid & 255;
    b = ii & 15;
    const int qi = ii >> 4;
    t = half ? qi : 31 - qi;
    j0 = 0; nc = 2 * t + 2; mode = 0;
  }

  const float SCALE = 0.12753102f;  // log2(e)/sqrt(128): exp2-domain scores
  const fx4 z4 = {0.f, 0.f, 0.f, 0.f};

  const unsigned short* kfb = Kf + ((size_t)b * 64) * FRAG_U16;
  const unsigned short* vfb = Vf + ((size_t)b * 64) * FRAG_U16;

  const int qb = t << 7;
  const int qw = qb + 32 * w;

  // Q fragments, pre-scaled, in registers for the whole kernel (32 VGPR).
  bfv8 qf[2][4];
#pragma unroll
  for (int qt = 0; qt < 2; ++qt) {
#pragma unroll
    for (int c = 0; c < 4; ++c) {
      const float* qp = Q + (((size_t)(b * NS + qw + qt * 16 + ln16)) << 7) + 32 * c + 8 * g;
      fx4 a0 = *(const fx4*)qp;
      fx4 a1 = *(const fx4*)(qp + 4);
      bfv8 tt_;
#pragma unroll
      for (int j = 0; j < 4; ++j) {
        tt_[j]     = (__bf16)(a0[j] * SCALE);
        tt_[j + 4] = (__bf16)(a1[j] * SCALE);
      }
      qf[qt][c] = tt_;
    }
  }

  fx4 acc[2][8];  // 64 accumulator regs (AGPR side of the unified file)
#pragma unroll
  for (int qt = 0; qt < 2; ++qt)
#pragma unroll
    for (int dt = 0; dt < 8; ++dt) acc[qt][dt] = z4;
  float mrun[2] = {-1e30f, -1e30f};
  float lsum[2] = {0.f, 0.f};

  const int nkvw = ((qw + 31) >> 6) + 1;  // causal limit (absolute kv blocks)
  const int jend = j0 + nc;

  // stage kv-block jb into the single LDS buffer. Wave w moves 1KB chunks:
  // lds dst is wave-uniform, HW adds lane*16.
#define STAGE(jb)                                                              \
  do {                                                                         \
    const unsigned char* gk = (const unsigned char*)(kfb + (size_t)(jb)*FRAG_U16); \
    const unsigned char* gv = (const unsigned char*)(vfb + (size_t)(jb)*FRAG_U16); \
    _Pragma("unroll")                                                          \
    for (int ii = 0; ii < 4; ++ii) {                                           \
      const int off = ii * 4096 + w * 1024;                                    \
      __builtin_amdgcn_global_load_lds((glob_u32*)(gk + off + lane * 16),      \
                                       (lds_u32*)(sm + off), 16, 0, 0);        \
      __builtin_amdgcn_global_load_lds((glob_u32*)(gv + off + lane * 16),      \
                                       (lds_u32*)(sm + 16384 + off), 16, 0, 0); \
    }                                                                          \
  } while (0)

  // prologue: stage first tile
  STAGE(j0);
  asm volatile("s_waitcnt vmcnt(0)" ::: "memory");
  __builtin_amdgcn_s_barrier();
  asm volatile("" ::: "memory");

  for (int jb = j0; jb < jend; ++jb) {
    if (jb < nkvw) {
      const unsigned char* kb = sm;
      const unsigned char* vb = sm + 16384;

      // ---- QK^T (swapped: A=K rows->kv, B=Q cols->q) ----
      fx4 s[2][4];
#pragma unroll
      for (int tt = 0; tt < 4; ++tt) { s[0][tt] = z4; s[1][tt] = z4; }
      __builtin_amdgcn_s_setprio(1);
#pragma unroll
      for (int tt = 0; tt < 4; ++tt) {
#pragma unroll
        for (int c = 0; c < 4; ++c) {
          bfv8 kfr = *(const bfv8*)(kb + tt * 4096 + c * 1024 + lane * 16);
          s[0][tt] = mfma16(kfr, qf[0][c], s[0][tt]);
          s[1][tt] = mfma16(kfr, qf[1][c], s[1][tt]);
        }
      }
      __builtin_amdgcn_s_setprio(0);

      // ---- causal mask (near-diagonal blocks only) ----
      const int kvb = jb << 6;
      if (kvb + 63 > qw) {
#pragma unroll
        for (int qt = 0; qt < 2; ++qt) {
          const int qrow = qw + qt * 16 + ln16;
#pragma unroll
          for (int tt = 0; tt < 4; ++tt)
#pragma unroll
            for (int r = 0; r < 4; ++r) {
              int kvpos = kvb + 16 * tt + 4 * g + r;
              if (kvpos > qrow) s[qt][tt][r] = -1e30f;
            }
        }
      }

      // ---- online softmax (exp2 domain, lane-local state, defer-max THR=8) ----
      bfv8 pb[2][2];
#pragma unroll
      for (int qt = 0; qt < 2; ++qt) {
        fx4 m4 = __builtin_elementwise_max(
            __builtin_elementwise_max(s[qt][0], s[qt][1]),
            __builtin_elementwise_max(s[qt][2], s[qt][3]));
        float pm = fmaxf(fmaxf(m4[0], m4[1]), fmaxf(m4[2], m4[3]));
        pm = fmaxf(pm, __shfl_xor(pm, 16));
        pm = fmaxf(pm, __shfl_xor(pm, 32));
        float mq = mrun[qt];
        if (__any(pm > mq + 8.0f)) {
          float mn = fmaxf(mq, pm);
          float f  = __builtin_amdgcn_exp2f(mq - mn);
          lsum[qt] *= f;
#pragma unroll
          for (int dt = 0; dt < 8; ++dt) acc[qt][dt] *= f;
          mrun[qt] = mn;
          mq = mn;
        }
#pragma unroll
        for (int tt = 0; tt < 4; ++tt)
#pragma unroll
          for (int r = 0; r < 4; ++r)
            s[qt][tt][r] = __builtin_amdgcn_exp2f(s[qt][tt][r] - mq);
        fx4 r4 = (s[qt][0] + s[qt][1]) + (s[qt][2] + s[qt][3]);
        float rs = (r4[0] + r4[1]) + (r4[2] + r4[3]);
        rs += __shfl_xor(rs, 16);
        rs += __shfl_xor(rs, 32);
        lsum[qt] += rs;
        // pack P^T: chunk c elem j<4 -> kv 32c+4g+j (tile 2c), j>=4 ->
        // 32c+16+4g+(j-4) (tile 2c+1) — matches Vfrag elem map exactly.
#pragma unroll
        for (int c = 0; c < 2; ++c) {
          bfv8 tt_;
#pragma unroll
          for (int j = 0; j < 4; ++j) {
            tt_[j]     = (__bf16)s[qt][2 * c][j];
            tt_[j + 4] = (__bf16)s[qt][2 * c + 1][j];
          }
          pb[qt][c] = tt_;
        }
      }

      // ---- PV (A = V^T rows->d, B = P^T cols->q) ----
      // V fragments read INLINE (no 32-reg prefetch -> fits the (256,3)
      // register cap; ds_read latency pipelined by compiler + 12 waves/CU).
      __builtin_amdgcn_s_setprio(1);
#pragma unroll
      for (int dt = 0; dt < 8; ++dt) {
#pragma unroll
        for (int c = 0; c < 2; ++c) {
          bfv8 vfr = *(const bfv8*)(vb + dt * 2048 + c * 1024 + lane * 16);
          acc[0][dt] = mfma16(vfr, pb[0][c], acc[0][dt]);
          acc[1][dt] = mfma16(vfr, pb[1][c], acc[1][dt]);
        }
      }
      __builtin_amdgcn_s_setprio(0);
    }

    // barrier B: all waves done reading this tile; then overwrite it.
    asm volatile("" ::: "memory");
    __builtin_amdgcn_s_barrier();
    if (jb + 1 < jend) {
      STAGE(jb + 1);
      asm volatile("s_waitcnt vmcnt(0)" ::: "memory");
    }
    // barrier A: next tile fully staged for all waves.
    __builtin_amdgcn_s_barrier();
    asm volatile("" ::: "memory");
  }
#undef STAGE

  // ---- epilogue per mode ----
  if (mode == 0) {  // final: O = acc/l
#pragma unroll
    for (int qt = 0; qt < 2; ++qt) {
      float inv = 1.0f / lsum[qt];
      float* ob = O + (((size_t)(b * NS + qw + qt * 16 + ln16)) << 7) + 4 * g;
#pragma unroll
      for (int dt = 0; dt < 8; ++dt) *(fx4*)(ob + 16 * dt) = acc[qt][dt] * inv;
    }
  } else {
    if (mode == 1) {  // chunk0: raw f32 acc -> O (merged later)
#pragma unroll
      for (int qt = 0; qt < 2; ++qt) {
        float* ob = O + (((size_t)(b * NS + qw + qt * 16 + ln16)) << 7) + 4 * g;
#pragma unroll
        for (int dt = 0; dt < 8; ++dt) *(fx4*)(ob + 16 * dt) = acc[qt][dt];
      }
    } else {  // chunk1: bf16 acc -> Pa
#pragma unroll
      for (int qt = 0; qt < 2; ++qt) {
        const int row = 32 * w + 16 * qt + ln16;
        unsigned short* pp =
            Pa + (((size_t)((b * 16 + (t - 16)) * 128 + row)) << 7) + 4 * g;
#pragma unroll
        for (int dt = 0; dt < 8; ++dt) {
          bfv4 t4;
#pragma unroll
          for (int j = 0; j < 4; ++j) t4[j] = (__bf16)acc[qt][dt][j];
          *(u16x4*)(pp + 16 * dt) = __builtin_bit_cast(u16x4, t4);
        }
      }
    }
    if (g == 0) {  // (m,l): Ml[b][t-16][slot][2][128]
      const int slot = mode - 1;
      float* mlp = Ml + (size_t)(((b * 16 + (t - 16)) * 2 + slot) * 2) * 128;
#pragma unroll
      for (int qt = 0; qt < 2; ++qt) {
        const int row = 32 * w + 16 * qt + ln16;
        mlp[row]       = mrun[qt];
        mlp[128 + row] = lsum[qt];
      }
    }
  }
}

// ---------------- merge: combine chunk0 (raw f32 in O) with chunk1 (bf16 Pa) ----------------
__global__ void __launch_bounds__(256) merge_kernel(
    float* __restrict__ O, const unsigned short* __restrict__ Pa,
    const float* __restrict__ Ml) {
  const int gid = blockIdx.x * 256 + threadIdx.x;  // 1,048,576 threads exact
  const int d4  = gid & 31;
  const int rg  = gid >> 5;       // global split-row id, 0..32767
  const int b   = rg >> 11;
  const int r2  = rg & 2047;
  const int tt  = r2 >> 7;        // tile t = 16+tt
  const int row = r2 & 127;

  const float* mlp = Ml + (size_t)((b * 16 + tt) * 4) * 128;
  const float m1 = mlp[row],       l1 = mlp[128 + row];
  const float m2 = mlp[256 + row], l2 = mlp[384 + row];
  const float m  = fmaxf(m1, m2);
  const float w1 = __builtin_amdgcn_exp2f(m1 - m);
  const float w2 = __builtin_amdgcn_exp2f(m2 - m);

  float* op = O + (((size_t)(b * NS + (16 + tt) * 128 + row)) << 7) + 4 * d4;
  fx4 a1 = *(const fx4*)op;
  const unsigned short* pp =
      Pa + (((size_t)((b * 16 + tt) * 128 + row)) << 7) + 4 * d4;
  bfv4 a2b = __builtin_bit_cast(bfv4, *(const u16x4*)pp);
  fx4 a2;
#pragma unroll
  for (int j = 0; j < 4; ++j) a2[j] = (float)a2b[j];

  const float inv = 1.0f / (w1 * l1 + w2 * l2);
  fx4 o = (a1 * w1 + a2 * w2) * inv;
  *(fx4*)op = o;
}

extern "C" void kernel_launch(void* const* d_in, const int* in_sizes, int n_in,
                              void* d_out, int out_size, void* d_ws, size_t ws_size,
                              hipStream_t stream) {
  (void)in_sizes; (void)n_in; (void)out_size;
  const float* Q = (const float*)d_in[0];
  const float* K = (const float*)d_in[1];
  const float* V = (const float*)d_in[2];
  float* O = (float*)d_out;

  unsigned short* Kf = (unsigned short*)d_ws;               // 16 MB
  unsigned short* Vf = Kf + (size_t)NB * NS * DH;           // +16 MB
  unsigned short* Pa = Vf + (size_t)NB * NS * DH;           // +8 MB  (bf16 partials)
  float*          Ml = (float*)((char*)d_ws + 41943040);    // +512 KB (m,l)

  const size_t NEED = 41943040 + 524288;  // 42,467,328 B
  const int split = (ws_size >= NEED) ? 1 : 0;

  prepack_kernel<<<dim3(NB * 64), dim3(256), 0, stream>>>(K, V, Kf, Vf);
  attn_kernel<<<dim3(split ? 768 : 512), dim3(256), 0, stream>>>(
      Q, Kf, Vf, O, Pa, Ml, split);
  if (split) merge_kernel<<<dim3(4096), dim3(256), 0, stream>>>(O, Pa, Ml);
}